// Round 1
// baseline (580.261 us; speedup 1.0000x reference)
//
#include <hip/hip_runtime.h>

typedef unsigned short u16;
typedef unsigned int   u32;
typedef __attribute__((ext_vector_type(8))) short bf16x8;  // 8 bf16 in 4 VGPRs
typedef __attribute__((ext_vector_type(4))) float f32x4;

#define LL 384
#define DP 128
#define SZROW ((size_t)LL * LL)   // 147456

// XOR-swizzled LDS tile addressing (128 bf16 per row, 16B groups) -> 2-way max
// bank aliasing on both row-wise writes and B-fragment (column-of-rows) reads.
#define SWZ(row, col) (((row) << 7) + (((((col) >> 3) ^ ((row) & 7)) << 3) | ((col) & 7)))

__device__ __forceinline__ u16 f2bf(float x) {
  u32 u = __builtin_bit_cast(u32, x);
  u = (u + 0x7FFFu + ((u >> 16) & 1u)) >> 16;   // RNE
  return (u16)u;
}
__device__ __forceinline__ float bf2f(u16 h) {
  return __builtin_bit_cast(float, ((u32)h) << 16);
}
__device__ __forceinline__ uint2 pack4(float a, float b, float c, float d) {
  uint2 p;
  p.x = (u32)f2bf(a) | ((u32)f2bf(b) << 16);
  p.y = (u32)f2bf(c) | ((u32)f2bf(d) << 16);
  return p;
}

// ---------------------------------------------------------------------------
// K0: weight prep. Wt[out][in] = W[in][out] * scale, bf16.
// m: 0=Wq(*1/sqrt(32)) 1=Wk(*1/384) 2=Wv 3=Wg 4=Wout
// ---------------------------------------------------------------------------
__global__ void k_prep(const float* __restrict__ Wq, const float* __restrict__ Wk,
                       const float* __restrict__ Wv, const float* __restrict__ Wg,
                       const float* __restrict__ Wout, u16* __restrict__ wbf) {
  int r = blockIdx.x, c = threadIdx.x, m = blockIdx.y;
  const float* W;
  float s = 1.0f;
  if (m == 0)      { W = Wq;  s = 0.17677669529663687f; }
  else if (m == 1) { W = Wk;  s = 1.0f / 384.0f; }
  else if (m == 2) { W = Wv; }
  else if (m == 3) { W = Wg; }
  else             { W = Wout; }
  wbf[m * DP * DP + r * DP + c] = f2bf(W[c * DP + r] * s);
}

// ---------------------------------------------------------------------------
// Wave-level GEMM: D[m][n] = sum_k A[m][k] B[k][n], M=32 rows (this wave),
// N=128, K=128. A = W rows (global, row-contiguous), B = swizzled LDS tile
// read as pn[n][k]. mfma_f32_16x16x32_bf16 frags:
//   A-frag: A[m = lane&15][k = (lane>>4)*8 + j]
//   B-frag: B[k = (lane>>4)*8 + j][n = lane&15]
//   D:      D[row = (lane>>4)*4 + reg][col = lane&15]
// ---------------------------------------------------------------------------
__device__ __forceinline__ void wave_gemm_128(const u16* __restrict__ W, const u16* pnl,
                                              int wave, int q, int r, f32x4 acc[2][8]) {
  const f32x4 FZ = {0.f, 0.f, 0.f, 0.f};
#pragma unroll
  for (int ms = 0; ms < 2; ++ms)
#pragma unroll
    for (int ns = 0; ns < 8; ++ns) acc[ms][ns] = FZ;
#pragma unroll
  for (int kc = 0; kc < 4; ++kc) {
    bf16x8 a0 = *(const bf16x8*)(W + (wave * 32 + r) * DP + kc * 32 + q * 8);
    bf16x8 a1 = *(const bf16x8*)(W + (wave * 32 + 16 + r) * DP + kc * 32 + q * 8);
#pragma unroll
    for (int ns = 0; ns < 8; ++ns) {
      bf16x8 b = *(const bf16x8*)(pnl + SWZ(ns * 16 + r, kc * 32 + q * 8));
      acc[0][ns] = __builtin_amdgcn_mfma_f32_16x16x32_bf16(a0, b, acc[0][ns], 0, 0, 0);
      acc[1][ns] = __builtin_amdgcn_mfma_f32_16x16x32_bf16(a1, b, acc[1][ns], 0, 0, 0);
    }
  }
}

// ---------------------------------------------------------------------------
// K1: LN(pair_t) + projections. Block = (ib, n): rows i = ib*128..+128 of the
// (n, i) plane. pn[n][i][:] = LN(pair[i][n][:]).
// Outputs: Q/K/G as [n][i][128] bf16, V transposed as Vt[n][c][i] bf16.
// ---------------------------------------------------------------------------
__global__ __launch_bounds__(256) void k1_ln_proj(
    const float* __restrict__ pair, const float* __restrict__ gamma_p,
    const float* __restrict__ beta_p, const u16* __restrict__ wbf,
    const float* __restrict__ bg, u16* __restrict__ Qb, u16* __restrict__ Kb,
    u16* __restrict__ Vtb, u16* __restrict__ Gb) {
  __shared__ u16 pn[DP * DP];
  const int ib = blockIdx.x, n = blockIdx.y;
  const int lane = threadIdx.x & 63, wave = threadIdx.x >> 6;
  const int q = lane >> 4, r = lane & 15;
  const int c0 = 2 * lane;
  const float g0 = gamma_p[c0], g1 = gamma_p[c0 + 1];
  const float be0 = beta_p[c0], be1 = beta_p[c0 + 1];

  for (int il = wave; il < 128; il += 4) {
    const float* rowp = pair + ((size_t)(ib * 128 + il) * LL + n) * DP;
    float2 x = *(const float2*)(rowp + c0);
    float s1 = x.x + x.y, s2 = x.x * x.x + x.y * x.y;
#pragma unroll
    for (int m = 32; m >= 1; m >>= 1) { s1 += __shfl_xor(s1, m); s2 += __shfl_xor(s2, m); }
    float mean = s1 * (1.0f / 128.0f);
    float rs = rsqrtf(s2 * (1.0f / 128.0f) - mean * mean + 1e-5f);
    float y0 = (x.x - mean) * rs * g0 + be0;
    float y1 = (x.y - mean) * rs * g1 + be1;
    *(u32*)(&pn[SWZ(il, c0)]) = (u32)f2bf(y0) | ((u32)f2bf(y1) << 16);
  }
  __syncthreads();

  f32x4 acc[2][8];

  // ---- Q ----
  wave_gemm_128(wbf, pn, wave, q, r, acc);
#pragma unroll
  for (int ms = 0; ms < 2; ++ms) {
    int ob = wave * 32 + ms * 16 + q * 4;
#pragma unroll
    for (int ns = 0; ns < 8; ++ns) {
      size_t base = ((size_t)n * LL + ib * 128 + ns * 16 + r) * DP + ob;
      *(uint2*)(Qb + base) = pack4(acc[ms][ns][0], acc[ms][ns][1], acc[ms][ns][2], acc[ms][ns][3]);
    }
  }
  // ---- K ----
  wave_gemm_128(wbf + DP * DP, pn, wave, q, r, acc);
#pragma unroll
  for (int ms = 0; ms < 2; ++ms) {
    int ob = wave * 32 + ms * 16 + q * 4;
#pragma unroll
    for (int ns = 0; ns < 8; ++ns) {
      size_t base = ((size_t)n * LL + ib * 128 + ns * 16 + r) * DP + ob;
      *(uint2*)(Kb + base) = pack4(acc[ms][ns][0], acc[ms][ns][1], acc[ms][ns][2], acc[ms][ns][3]);
    }
  }
  // ---- V (store transposed: Vt[n][c][j]) ----
  wave_gemm_128(wbf + 2 * DP * DP, pn, wave, q, r, acc);
#pragma unroll
  for (int ms = 0; ms < 2; ++ms) {
    int ob = wave * 32 + ms * 16 + q * 4;
#pragma unroll
    for (int ns = 0; ns < 8; ++ns)
#pragma unroll
      for (int reg = 0; reg < 4; ++reg)
        Vtb[((size_t)n * DP + ob + reg) * LL + ib * 128 + ns * 16 + r] = f2bf(acc[ms][ns][reg]);
  }
  // ---- G = sigmoid(pn@Wg + bg) ----
  wave_gemm_128(wbf + 3 * DP * DP, pn, wave, q, r, acc);
#pragma unroll
  for (int ms = 0; ms < 2; ++ms) {
    int ob = wave * 32 + ms * 16 + q * 4;
    f32x4 bgv = *(const f32x4*)(bg + ob);
#pragma unroll
    for (int ns = 0; ns < 8; ++ns) {
      float gv[4];
#pragma unroll
      for (int reg = 0; reg < 4; ++reg) {
        float x = acc[ms][ns][reg] + bgv[reg];
        gv[reg] = 1.0f / (1.0f + __expf(-x));
      }
      size_t base = ((size_t)n * LL + ib * 128 + ns * 16 + r) * DP + ob;
      *(uint2*)(Gb + base) = pack4(gv[0], gv[1], gv[2], gv[3]);
    }
  }
}

// ---------------------------------------------------------------------------
// K2a: bias-LN logit plane. Row id = j*384 + i (sequential reads of bias).
// part[(32+h)][i][j] = LN(bias[j][i][:]) . Wb[:,h]   (all fp32)
// ---------------------------------------------------------------------------
__global__ __launch_bounds__(256) void k2a_bias(
    const float* __restrict__ bias, const float* __restrict__ gamma_b,
    const float* __restrict__ beta_b, const float* __restrict__ Wb,
    float* __restrict__ part) {
  const int lane = threadIdx.x & 63, wave = threadIdx.x >> 6;
  const int row = blockIdx.x * 4 + wave;
  const int i = row % LL, j = row / LL;
  const int c0 = 2 * lane;
  const float* src = bias + (size_t)row * DP;
  float2 x = *(const float2*)(src + c0);
  float s1 = x.x + x.y, s2 = x.x * x.x + x.y * x.y;
#pragma unroll
  for (int m = 32; m >= 1; m >>= 1) { s1 += __shfl_xor(s1, m); s2 += __shfl_xor(s2, m); }
  float mean = s1 * (1.0f / 128.0f);
  float rs = rsqrtf(s2 * (1.0f / 128.0f) - mean * mean + 1e-5f);
  float y0 = (x.x - mean) * rs * gamma_b[c0] + beta_b[c0];
  float y1 = (x.y - mean) * rs * gamma_b[c0 + 1] + beta_b[c0 + 1];
  f32x4 w0 = *(const f32x4*)(Wb + c0 * 4);
  f32x4 w1 = *(const f32x4*)(Wb + c0 * 4 + 4);
  float p0 = y0 * w0[0] + y1 * w1[0];
  float p1 = y0 * w0[1] + y1 * w1[1];
  float p2 = y0 * w0[2] + y1 * w1[2];
  float p3 = y0 * w0[3] + y1 * w1[3];
#pragma unroll
  for (int m = 32; m >= 1; m >>= 1) {
    p0 += __shfl_xor(p0, m); p1 += __shfl_xor(p1, m);
    p2 += __shfl_xor(p2, m); p3 += __shfl_xor(p3, m);
  }
  if (lane == 0) {
    size_t o = (size_t)i * LL + j;
    part[(size_t)32 * SZROW + o] = p0;
    part[(size_t)33 * SZROW + o] = p1;
    part[(size_t)34 * SZROW + o] = p2;
    part[(size_t)35 * SZROW + o] = p3;
  }
}

// ---------------------------------------------------------------------------
// K2b: attn_h[i][j] += sum_{n in chunk, k} Q[n][i][h,k] K[n][j][h,k]
// Grid (it, jt, nc) = (8, 8, 8); 48x48 tile; wave = head. Split-K partials
// to part[nc*4+h]. Fragments gathered directly from L1/L2, no LDS.
// ---------------------------------------------------------------------------
__global__ __launch_bounds__(256) void k2b_qk(const u16* __restrict__ Qb,
                                              const u16* __restrict__ Kb,
                                              float* __restrict__ part) {
  const int it = blockIdx.x, jt = blockIdx.y, nc = blockIdx.z;
  const int lane = threadIdx.x & 63, h = threadIdx.x >> 6;
  const int q = lane >> 4, r = lane & 15;
  const f32x4 FZ = {0.f, 0.f, 0.f, 0.f};
  f32x4 acc[3][3];
#pragma unroll
  for (int a = 0; a < 3; ++a)
#pragma unroll
    for (int b = 0; b < 3; ++b) acc[a][b] = FZ;
  const int coff = h * 32 + q * 8;
#pragma unroll 2
  for (int n = nc * 48; n < nc * 48 + 48; ++n) {
    const u16* Qp = Qb + ((size_t)n * LL + it * 48) * DP + coff;
    const u16* Kp = Kb + ((size_t)n * LL + jt * 48) * DP + coff;
    bf16x8 av[3], bv[3];
#pragma unroll
    for (int s = 0; s < 3; ++s) {
      av[s] = *(const bf16x8*)(Qp + (s * 16 + r) * DP);
      bv[s] = *(const bf16x8*)(Kp + (s * 16 + r) * DP);
    }
#pragma unroll
    for (int is = 0; is < 3; ++is)
#pragma unroll
      for (int js = 0; js < 3; ++js)
        acc[is][js] = __builtin_amdgcn_mfma_f32_16x16x32_bf16(av[is], bv[js], acc[is][js], 0, 0, 0);
  }
  float* dst = part + (size_t)(nc * 4 + h) * SZROW;
#pragma unroll
  for (int is = 0; is < 3; ++is)
#pragma unroll
    for (int js = 0; js < 3; ++js)
#pragma unroll
      for (int reg = 0; reg < 4; ++reg)
        dst[(size_t)(it * 48 + is * 16 + q * 4 + reg) * LL + jt * 48 + js * 16 + r] =
            acc[is][js][reg];
}

// ---------------------------------------------------------------------------
// K3: logits = sum of 9 partial planes; softmax over j; a -> bf16 [h][i][j].
// ---------------------------------------------------------------------------
__global__ __launch_bounds__(384) void k3_softmax(const float* __restrict__ part,
                                                  u16* __restrict__ abf) {
  const int i = blockIdx.x, h = blockIdx.y, j = threadIdx.x;
  __shared__ float red[6];
  float l = 0.f;
#pragma unroll
  for (int c = 0; c < 9; ++c) l += part[(size_t)(c * 4 + h) * SZROW + (size_t)i * LL + j];
  float m = l;
#pragma unroll
  for (int s = 32; s >= 1; s >>= 1) m = fmaxf(m, __shfl_xor(m, s));
  const int wv = threadIdx.x >> 6;
  if ((threadIdx.x & 63) == 0) red[wv] = m;
  __syncthreads();
  m = fmaxf(fmaxf(fmaxf(red[0], red[1]), fmaxf(red[2], red[3])), fmaxf(red[4], red[5]));
  float e = __expf(l - m);
  float s = e;
#pragma unroll
  for (int t = 32; t >= 1; t >>= 1) s += __shfl_xor(s, t);
  __syncthreads();
  if ((threadIdx.x & 63) == 0) red[wv] = s;
  __syncthreads();
  s = red[0] + red[1] + red[2] + red[3] + red[4] + red[5];
  abf[((size_t)h * LL + i) * LL + j] = f2bf(e / s);
}

// ---------------------------------------------------------------------------
// K4: O[n][i][h,d] = sum_j a_h[i][j] V[n][j][h,d]; gate; @Wout + bout;
// store transposed: out[i][n][:]. Block = (ib, n); wave = head for PV.
// ---------------------------------------------------------------------------
__global__ __launch_bounds__(256) void k4_out(
    const u16* __restrict__ abf, const u16* __restrict__ Vtb,
    const u16* __restrict__ Gb, const u16* __restrict__ Wot,
    const float* __restrict__ bout, float* __restrict__ out) {
  __shared__ u16 go[DP * DP];
  const int ib = blockIdx.x, n = blockIdx.y;
  const int lane = threadIdx.x & 63, wave = threadIdx.x >> 6;
  const int h = wave;
  const int q = lane >> 4, r = lane & 15;
  const f32x4 FZ = {0.f, 0.f, 0.f, 0.f};
  f32x4 acc[8][2];
#pragma unroll
  for (int is = 0; is < 8; ++is) { acc[is][0] = FZ; acc[is][1] = FZ; }

#pragma unroll 2
  for (int kc = 0; kc < 12; ++kc) {
    const u16* Vp = Vtb + ((size_t)n * DP + h * 32) * LL + kc * 32 + q * 8;
    bf16x8 b0 = *(const bf16x8*)(Vp + (size_t)r * LL);
    bf16x8 b1 = *(const bf16x8*)(Vp + (size_t)(16 + r) * LL);
#pragma unroll
    for (int is = 0; is < 8; ++is) {
      bf16x8 a = *(const bf16x8*)(abf + ((size_t)h * LL + ib * 128 + is * 16 + r) * LL +
                                  kc * 32 + q * 8);
      acc[is][0] = __builtin_amdgcn_mfma_f32_16x16x32_bf16(a, b0, acc[is][0], 0, 0, 0);
      acc[is][1] = __builtin_amdgcn_mfma_f32_16x16x32_bf16(a, b1, acc[is][1], 0, 0, 0);
    }
  }
  // gate + stash go (bf16) in swizzled LDS
#pragma unroll
  for (int is = 0; is < 8; ++is)
#pragma unroll
    for (int ds = 0; ds < 2; ++ds) {
      int c = h * 32 + ds * 16 + r;
#pragma unroll
      for (int reg = 0; reg < 4; ++reg) {
        int il = is * 16 + q * 4 + reg;
        float g = bf2f(Gb[((size_t)n * LL + ib * 128 + il) * DP + c]);
        go[SWZ(il, c)] = f2bf(g * acc[is][ds][reg]);
      }
    }
  __syncthreads();

  // out[i][co] = go[i][:] @ Wout ; computed as D[co][i] so co is reg-contig.
  f32x4 acc2[2][8];
  wave_gemm_128(Wot, go, wave, q, r, acc2);
#pragma unroll
  for (int ms = 0; ms < 2; ++ms) {
    int co = wave * 32 + ms * 16 + q * 4;
    f32x4 bo = *(const f32x4*)(bout + co);
#pragma unroll
    for (int ns = 0; ns < 8; ++ns) {
      f32x4 v = acc2[ms][ns] + bo;
      *(f32x4*)(out + ((size_t)(ib * 128 + ns * 16 + r) * LL + n) * DP + co) = v;
    }
  }
}

// ---------------------------------------------------------------------------
extern "C" void kernel_launch(void* const* d_in, const int* in_sizes, int n_in,
                              void* d_out, int out_size, void* d_ws, size_t ws_size,
                              hipStream_t stream) {
  const float* pair    = (const float*)d_in[0];
  const float* bias    = (const float*)d_in[1];
  const float* gamma_p = (const float*)d_in[2];
  const float* beta_p  = (const float*)d_in[3];
  const float* gamma_b = (const float*)d_in[4];
  const float* beta_b  = (const float*)d_in[5];
  const float* Wq      = (const float*)d_in[6];
  const float* Wk      = (const float*)d_in[7];
  const float* Wv      = (const float*)d_in[8];
  const float* Wb      = (const float*)d_in[9];
  const float* Wg      = (const float*)d_in[10];
  const float* bg      = (const float*)d_in[11];
  const float* Wout    = (const float*)d_in[12];
  const float* bout    = (const float*)d_in[13];

  // Q,K (bf16) live inside d_out: 2 * 18874368 u16 == out_size * 4 bytes.
  // They are fully consumed by k2b before k4 overwrites d_out with the result.
  u16* Qb = (u16*)d_out;
  u16* Kb = Qb + (size_t)LL * LL * DP;

  char* ws = (char*)d_ws;
  const size_t BF_PLANE = (size_t)LL * LL * DP * 2;  // 37748736 B
  u16*   Vtb  = (u16*)ws;
  u16*   Gb   = (u16*)(ws + BF_PLANE);
  float* part = (float*)(ws + 2 * BF_PLANE);                     // 36 planes fp32
  u16*   abf  = (u16*)(ws + 2 * BF_PLANE + 36 * SZROW * 4);
  u16*   wbf  = (u16*)(ws + 2 * BF_PLANE + 36 * SZROW * 4 + 4 * SZROW * 2);
  float* out  = (float*)d_out;

  k_prep<<<dim3(128, 5), 128, 0, stream>>>(Wq, Wk, Wv, Wg, Wout, wbf);
  k1_ln_proj<<<dim3(3, 384), 256, 0, stream>>>(pair, gamma_p, beta_p, wbf, bg, Qb, Kb, Vtb, Gb);
  k2a_bias<<<dim3(36864), 256, 0, stream>>>(bias, gamma_b, beta_b, Wb, part);
  k2b_qk<<<dim3(8, 8, 8), 256, 0, stream>>>(Qb, Kb, part);
  k3_softmax<<<dim3(384, 4), 384, 0, stream>>>(part, abf);
  k4_out<<<dim3(3, 384), 256, 0, stream>>>(abf, Vtb, Gb, wbf + 4 * DP * DP, bout, out);
}

// Round 2
// 452.184 us; speedup vs baseline: 1.2832x; 1.2832x over previous
//
#include <hip/hip_runtime.h>

typedef unsigned short u16;
typedef unsigned int   u32;
typedef __attribute__((ext_vector_type(8))) short bf16x8;  // 8 bf16 in 4 VGPRs
typedef __attribute__((ext_vector_type(4))) float f32x4;

#define LL 384
#define DP 128
#define SZROW ((size_t)LL * LL)   // 147456

// XOR-swizzled LDS tile addressing (128 bf16 per row, 16B groups) -> 2-way max
// bank aliasing on both row-wise writes and B-fragment (column-of-rows) reads.
#define SWZ(row, col) (((row) << 7) + (((((col) >> 3) ^ ((row) & 7)) << 3) | ((col) & 7)))

__device__ __forceinline__ u16 f2bf(float x) {
  u32 u = __builtin_bit_cast(u32, x);
  u = (u + 0x7FFFu + ((u >> 16) & 1u)) >> 16;   // RNE
  return (u16)u;
}
__device__ __forceinline__ float bf2f(u16 h) {
  return __builtin_bit_cast(float, ((u32)h) << 16);
}
__device__ __forceinline__ uint2 pack4(float a, float b, float c, float d) {
  uint2 p;
  p.x = (u32)f2bf(a) | ((u32)f2bf(b) << 16);
  p.y = (u32)f2bf(c) | ((u32)f2bf(d) << 16);
  return p;
}

// ---------------------------------------------------------------------------
// K0: weight prep. Wt[out][in] = W[in][out] * scale, bf16.
// m: 0=Wq(*1/sqrt(32)) 1=Wk(*1/384) 2=Wv 3=Wg 4=Wout
// ---------------------------------------------------------------------------
__global__ void k_prep(const float* __restrict__ Wq, const float* __restrict__ Wk,
                       const float* __restrict__ Wv, const float* __restrict__ Wg,
                       const float* __restrict__ Wout, u16* __restrict__ wbf) {
  int r = blockIdx.x, c = threadIdx.x, m = blockIdx.y;
  const float* W;
  float s = 1.0f;
  if (m == 0)      { W = Wq;  s = 0.17677669529663687f; }
  else if (m == 1) { W = Wk;  s = 1.0f / 384.0f; }
  else if (m == 2) { W = Wv; }
  else if (m == 3) { W = Wg; }
  else             { W = Wout; }
  wbf[m * DP * DP + r * DP + c] = f2bf(W[c * DP + r] * s);
}

// ---------------------------------------------------------------------------
// Wave-level GEMM: D[m][i] = sum_k A[m][k] * tile[i][k]   (D = W . tile^T)
// M = 32 rows (this wave), N = NS*16 i-rows, K = 128.
// mfma_f32_16x16x32_bf16 frags:
//   A-frag: A[m = lane&15][k = (lane>>4)*8 + j]
//   B-frag: B[k = (lane>>4)*8 + j][n = lane&15]
//   D:      D[row = (lane>>4)*4 + reg][col = lane&15]
// ---------------------------------------------------------------------------
template <int NS>
__device__ __forceinline__ void wave_gemm(const u16* __restrict__ W, const u16* pnl,
                                          int wave, int q, int r, f32x4 (&acc)[2][NS]) {
  const f32x4 FZ = {0.f, 0.f, 0.f, 0.f};
#pragma unroll
  for (int ms = 0; ms < 2; ++ms)
#pragma unroll
    for (int ns = 0; ns < NS; ++ns) acc[ms][ns] = FZ;
#pragma unroll
  for (int kc = 0; kc < 4; ++kc) {
    bf16x8 a0 = *(const bf16x8*)(W + (wave * 32 + r) * DP + kc * 32 + q * 8);
    bf16x8 a1 = *(const bf16x8*)(W + (wave * 32 + 16 + r) * DP + kc * 32 + q * 8);
#pragma unroll
    for (int ns = 0; ns < NS; ++ns) {
      bf16x8 b = *(const bf16x8*)(pnl + SWZ(ns * 16 + r, kc * 32 + q * 8));
      acc[0][ns] = __builtin_amdgcn_mfma_f32_16x16x32_bf16(a0, b, acc[0][ns], 0, 0, 0);
      acc[1][ns] = __builtin_amdgcn_mfma_f32_16x16x32_bf16(a1, b, acc[1][ns], 0, 0, 0);
    }
  }
}

// ---------------------------------------------------------------------------
// K1: LN(pair_t) + 4 projections. Block = (ib, n): 64 i-rows of the (n,i)
// plane. pn[i][:] = LN(pair[i][n][:]).
// Outputs: Q/K as [n][i][128] bf16; V and G transposed: [n][c][i] bf16
// (via padded LDS transpose tile -> fully vectorized 16B/lane stores).
// ---------------------------------------------------------------------------
__global__ __launch_bounds__(256) void k1_ln_proj(
    const float* __restrict__ pair, const float* __restrict__ gamma_p,
    const float* __restrict__ beta_p, const u16* __restrict__ wbf,
    const float* __restrict__ bg, u16* __restrict__ Qb, u16* __restrict__ Kb,
    u16* __restrict__ Vtb, u16* __restrict__ Gtb) {
  __shared__ u16 pn[64 * 128];   // swizzled LN tile
  __shared__ u16 T[128 * 72];    // padded transpose staging tile
  const int ib = blockIdx.x, n = blockIdx.y;
  const int tid = threadIdx.x;
  const int lane = tid & 63, wave = tid >> 6;
  const int q = lane >> 4, r = lane & 15;
  const int l32 = lane & 31, half = lane >> 5;
  const int c0 = l32 * 4;
  const float4 gm = *(const float4*)(gamma_p + c0);
  const float4 bt = *(const float4*)(beta_p + c0);

  // ---- LN: 2 rows/wave/iter, 32 lanes x float4 per row ----
#pragma unroll
  for (int it = 0; it < 8; ++it) {
    const int il = it * 8 + wave * 2 + half;
    const float* rowp = pair + ((size_t)(ib * 64 + il) * LL + n) * DP + c0;
    float4 x = *(const float4*)rowp;
    float s1 = x.x + x.y + x.z + x.w;
    float s2 = x.x * x.x + x.y * x.y + x.z * x.z + x.w * x.w;
#pragma unroll
    for (int m = 16; m >= 1; m >>= 1) { s1 += __shfl_xor(s1, m); s2 += __shfl_xor(s2, m); }
    float mean = s1 * (1.0f / 128.0f);
    float rs = rsqrtf(s2 * (1.0f / 128.0f) - mean * mean + 1e-5f);
    *(uint2*)(&pn[SWZ(il, c0)]) =
        pack4((x.x - mean) * rs * gm.x + bt.x, (x.y - mean) * rs * gm.y + bt.y,
              (x.z - mean) * rs * gm.z + bt.z, (x.w - mean) * rs * gm.w + bt.w);
  }
  __syncthreads();

  f32x4 acc[2][4];

  // ---- Q ----
  wave_gemm<4>(wbf, pn, wave, q, r, acc);
#pragma unroll
  for (int ms = 0; ms < 2; ++ms) {
    int ob = wave * 32 + ms * 16 + q * 4;
#pragma unroll
    for (int ns = 0; ns < 4; ++ns) {
      size_t base = ((size_t)n * LL + ib * 64 + ns * 16 + r) * DP + ob;
      *(uint2*)(Qb + base) = pack4(acc[ms][ns][0], acc[ms][ns][1], acc[ms][ns][2], acc[ms][ns][3]);
    }
  }
  // ---- K ----
  wave_gemm<4>(wbf + DP * DP, pn, wave, q, r, acc);
#pragma unroll
  for (int ms = 0; ms < 2; ++ms) {
    int ob = wave * 32 + ms * 16 + q * 4;
#pragma unroll
    for (int ns = 0; ns < 4; ++ns) {
      size_t base = ((size_t)n * LL + ib * 64 + ns * 16 + r) * DP + ob;
      *(uint2*)(Kb + base) = pack4(acc[ms][ns][0], acc[ms][ns][1], acc[ms][ns][2], acc[ms][ns][3]);
    }
  }
  // ---- V: transpose via T, coalesced store Vt[n][c][i] ----
  wave_gemm<4>(wbf + 2 * DP * DP, pn, wave, q, r, acc);
#pragma unroll
  for (int ms = 0; ms < 2; ++ms)
#pragma unroll
    for (int ns = 0; ns < 4; ++ns)
#pragma unroll
      for (int reg = 0; reg < 4; ++reg)
        T[(wave * 32 + ms * 16 + q * 4 + reg) * 72 + ns * 16 + r] = f2bf(acc[ms][ns][reg]);
  __syncthreads();
#pragma unroll
  for (int it = 0; it < 4; ++it) {
    int c = it * 32 + (tid >> 3);
    int il2 = (tid & 7) * 8;
    *(uint4*)(Vtb + ((size_t)n * DP + c) * LL + ib * 64 + il2) =
        *(const uint4*)(T + c * 72 + il2);
  }
  // ---- G = sigmoid(pn@Wg + bg): transpose via T, store Gt[n][c][i] ----
  wave_gemm<4>(wbf + 3 * DP * DP, pn, wave, q, r, acc);
  __syncthreads();   // all V coop-reads of T done before overwrite
#pragma unroll
  for (int ms = 0; ms < 2; ++ms) {
    f32x4 bgv = *(const f32x4*)(bg + wave * 32 + ms * 16 + q * 4);
#pragma unroll
    for (int ns = 0; ns < 4; ++ns)
#pragma unroll
      for (int reg = 0; reg < 4; ++reg) {
        float x = acc[ms][ns][reg] + bgv[reg];
        T[(wave * 32 + ms * 16 + q * 4 + reg) * 72 + ns * 16 + r] =
            f2bf(1.0f / (1.0f + __expf(-x)));
      }
  }
  __syncthreads();
#pragma unroll
  for (int it = 0; it < 4; ++it) {
    int c = it * 32 + (tid >> 3);
    int il2 = (tid & 7) * 8;
    *(uint4*)(Gtb + ((size_t)n * DP + c) * LL + ib * 64 + il2) =
        *(const uint4*)(T + c * 72 + il2);
  }
}

// ---------------------------------------------------------------------------
// K2a: bias-LN logit plane. part[(32+h)][i][j] = LN(bias[j][i][:]) . Wb[:,h]
// 2 rows/wave (32 lanes x float4 each), fp32 throughout.
// ---------------------------------------------------------------------------
__global__ __launch_bounds__(256) void k2a_bias(
    const float* __restrict__ bias, const float* __restrict__ gamma_b,
    const float* __restrict__ beta_b, const float* __restrict__ Wb,
    float* __restrict__ part) {
  const int lane = threadIdx.x & 63, wave = threadIdx.x >> 6;
  const int l32 = lane & 31, half = lane >> 5;
  const int row = blockIdx.x * 8 + wave * 2 + half;
  const int i = row % LL, j = row / LL;
  const int c0 = l32 * 4;
  float4 x = *(const float4*)(bias + (size_t)row * DP + c0);
  float s1 = x.x + x.y + x.z + x.w;
  float s2 = x.x * x.x + x.y * x.y + x.z * x.z + x.w * x.w;
#pragma unroll
  for (int m = 16; m >= 1; m >>= 1) { s1 += __shfl_xor(s1, m); s2 += __shfl_xor(s2, m); }
  float mean = s1 * (1.0f / 128.0f);
  float rs = rsqrtf(s2 * (1.0f / 128.0f) - mean * mean + 1e-5f);
  const float4 gm = *(const float4*)(gamma_b + c0);
  const float4 bt = *(const float4*)(beta_b + c0);
  float y0 = (x.x - mean) * rs * gm.x + bt.x;
  float y1 = (x.y - mean) * rs * gm.y + bt.y;
  float y2 = (x.z - mean) * rs * gm.z + bt.z;
  float y3 = (x.w - mean) * rs * gm.w + bt.w;
  f32x4 w0 = *(const f32x4*)(Wb + (c0 + 0) * 4);
  f32x4 w1 = *(const f32x4*)(Wb + (c0 + 1) * 4);
  f32x4 w2 = *(const f32x4*)(Wb + (c0 + 2) * 4);
  f32x4 w3 = *(const f32x4*)(Wb + (c0 + 3) * 4);
  f32x4 pv = y0 * w0 + y1 * w1 + y2 * w2 + y3 * w3;
#pragma unroll
  for (int m = 16; m >= 1; m >>= 1) {
    pv[0] += __shfl_xor(pv[0], m); pv[1] += __shfl_xor(pv[1], m);
    pv[2] += __shfl_xor(pv[2], m); pv[3] += __shfl_xor(pv[3], m);
  }
  if (l32 == 0) {
    size_t o = (size_t)i * LL + j;
    part[(size_t)32 * SZROW + o] = pv[0];
    part[(size_t)33 * SZROW + o] = pv[1];
    part[(size_t)34 * SZROW + o] = pv[2];
    part[(size_t)35 * SZROW + o] = pv[3];
  }
}

// ---------------------------------------------------------------------------
// K2b: attn_h[i][j] += sum_{n in chunk, k} Q[n][i][h,k] K[n][j][h,k]
// Grid (it, jt, nc) = (8, 8, 8); 48x48 tile; wave = head. Split-K partials
// to part[nc*4+h]. Fragments gathered directly from L1/L2, no LDS.
// ---------------------------------------------------------------------------
__global__ __launch_bounds__(256) void k2b_qk(const u16* __restrict__ Qb,
                                              const u16* __restrict__ Kb,
                                              float* __restrict__ part) {
  const int it = blockIdx.x, jt = blockIdx.y, nc = blockIdx.z;
  const int lane = threadIdx.x & 63, h = threadIdx.x >> 6;
  const int q = lane >> 4, r = lane & 15;
  const f32x4 FZ = {0.f, 0.f, 0.f, 0.f};
  f32x4 acc[3][3];
#pragma unroll
  for (int a = 0; a < 3; ++a)
#pragma unroll
    for (int b = 0; b < 3; ++b) acc[a][b] = FZ;
  const int coff = h * 32 + q * 8;
#pragma unroll 2
  for (int n = nc * 48; n < nc * 48 + 48; ++n) {
    const u16* Qp = Qb + ((size_t)n * LL + it * 48) * DP + coff;
    const u16* Kp = Kb + ((size_t)n * LL + jt * 48) * DP + coff;
    bf16x8 av[3], bv[3];
#pragma unroll
    for (int s = 0; s < 3; ++s) {
      av[s] = *(const bf16x8*)(Qp + (s * 16 + r) * DP);
      bv[s] = *(const bf16x8*)(Kp + (s * 16 + r) * DP);
    }
#pragma unroll
    for (int is = 0; is < 3; ++is)
#pragma unroll
      for (int js = 0; js < 3; ++js)
        acc[is][js] = __builtin_amdgcn_mfma_f32_16x16x32_bf16(av[is], bv[js], acc[is][js], 0, 0, 0);
  }
  float* dst = part + (size_t)(nc * 4 + h) * SZROW;
#pragma unroll
  for (int is = 0; is < 3; ++is)
#pragma unroll
    for (int js = 0; js < 3; ++js)
#pragma unroll
      for (int reg = 0; reg < 4; ++reg)
        dst[(size_t)(it * 48 + is * 16 + q * 4 + reg) * LL + jt * 48 + js * 16 + r] =
            acc[is][js][reg];
}

// ---------------------------------------------------------------------------
// K3: logits = sum of 9 partial planes; softmax over j; a -> bf16 [h][i][j].
// ---------------------------------------------------------------------------
__global__ __launch_bounds__(384) void k3_softmax(const float* __restrict__ part,
                                                  u16* __restrict__ abf) {
  const int i = blockIdx.x, h = blockIdx.y, j = threadIdx.x;
  __shared__ float red[6];
  float l = 0.f;
#pragma unroll
  for (int c = 0; c < 9; ++c) l += part[(size_t)(c * 4 + h) * SZROW + (size_t)i * LL + j];
  float m = l;
#pragma unroll
  for (int s = 32; s >= 1; s >>= 1) m = fmaxf(m, __shfl_xor(m, s));
  const int wv = threadIdx.x >> 6;
  if ((threadIdx.x & 63) == 0) red[wv] = m;
  __syncthreads();
  m = fmaxf(fmaxf(fmaxf(red[0], red[1]), fmaxf(red[2], red[3])), fmaxf(red[4], red[5]));
  float e = __expf(l - m);
  float s = e;
#pragma unroll
  for (int t = 32; t >= 1; t >>= 1) s += __shfl_xor(s, t);
  __syncthreads();
  if ((threadIdx.x & 63) == 0) red[wv] = s;
  __syncthreads();
  s = red[0] + red[1] + red[2] + red[3] + red[4] + red[5];
  abf[((size_t)h * LL + i) * LL + j] = f2bf(e / s);
}

// ---------------------------------------------------------------------------
// K4: O[n][i][h,d] = sum_j a_h[i][j] V[n][j][h,d]; gate; @Wout + bout;
// store transposed: out[i][n][:]. Block = (ib 64-rows, n); wave = head for PV.
// ---------------------------------------------------------------------------
__global__ __launch_bounds__(256) void k4_out(
    const u16* __restrict__ abf, const u16* __restrict__ Vtb,
    const u16* __restrict__ Gtb, const u16* __restrict__ Wot,
    const float* __restrict__ bout, float* __restrict__ out) {
  __shared__ u16 go[64 * 128];
  const int ib = blockIdx.x, n = blockIdx.y;
  const int lane = threadIdx.x & 63, wave = threadIdx.x >> 6;
  const int h = wave;
  const int q = lane >> 4, r = lane & 15;
  const f32x4 FZ = {0.f, 0.f, 0.f, 0.f};
  f32x4 acc[4][2];
#pragma unroll
  for (int is = 0; is < 4; ++is) { acc[is][0] = FZ; acc[is][1] = FZ; }

#pragma unroll 2
  for (int kc = 0; kc < 12; ++kc) {
    const u16* Vp = Vtb + ((size_t)n * DP + h * 32) * LL + kc * 32 + q * 8;
    bf16x8 b0 = *(const bf16x8*)(Vp + (size_t)r * LL);
    bf16x8 b1 = *(const bf16x8*)(Vp + (size_t)(16 + r) * LL);
#pragma unroll
    for (int is = 0; is < 4; ++is) {
      bf16x8 a = *(const bf16x8*)(abf + ((size_t)h * LL + ib * 64 + is * 16 + r) * LL +
                                  kc * 32 + q * 8);
      acc[is][0] = __builtin_amdgcn_mfma_f32_16x16x32_bf16(a, b0, acc[is][0], 0, 0, 0);
      acc[is][1] = __builtin_amdgcn_mfma_f32_16x16x32_bf16(a, b1, acc[is][1], 0, 0, 0);
    }
  }
  // gate (8B vector loads from Gt) + stash go (bf16) in swizzled LDS
#pragma unroll
  for (int is = 0; is < 4; ++is)
#pragma unroll
    for (int ds = 0; ds < 2; ++ds) {
      int c = h * 32 + ds * 16 + r;
      uint2 gp = *(const uint2*)(Gtb + ((size_t)n * DP + c) * LL + ib * 64 + is * 16 + q * 4);
      float g0 = bf2f((u16)(gp.x & 0xffff)), g1 = bf2f((u16)(gp.x >> 16));
      float g2 = bf2f((u16)(gp.y & 0xffff)), g3 = bf2f((u16)(gp.y >> 16));
      int il = is * 16 + q * 4;
      go[SWZ(il + 0, c)] = f2bf(g0 * acc[is][ds][0]);
      go[SWZ(il + 1, c)] = f2bf(g1 * acc[is][ds][1]);
      go[SWZ(il + 2, c)] = f2bf(g2 * acc[is][ds][2]);
      go[SWZ(il + 3, c)] = f2bf(g3 * acc[is][ds][3]);
    }
  __syncthreads();

  // out[i][co] = go[i][:] @ Wout ; computed as D[co][i] so co is reg-contig.
  f32x4 acc2[2][4];
  wave_gemm<4>(Wot, go, wave, q, r, acc2);
#pragma unroll
  for (int ms = 0; ms < 2; ++ms) {
    int co = wave * 32 + ms * 16 + q * 4;
    f32x4 bo = *(const f32x4*)(bout + co);
#pragma unroll
    for (int ns = 0; ns < 4; ++ns) {
      f32x4 v = acc2[ms][ns] + bo;
      *(f32x4*)(out + ((size_t)(ib * 64 + ns * 16 + r) * LL + n) * DP + co) = v;
    }
  }
}

// ---------------------------------------------------------------------------
extern "C" void kernel_launch(void* const* d_in, const int* in_sizes, int n_in,
                              void* d_out, int out_size, void* d_ws, size_t ws_size,
                              hipStream_t stream) {
  const float* pair    = (const float*)d_in[0];
  const float* bias    = (const float*)d_in[1];
  const float* gamma_p = (const float*)d_in[2];
  const float* beta_p  = (const float*)d_in[3];
  const float* gamma_b = (const float*)d_in[4];
  const float* beta_b  = (const float*)d_in[5];
  const float* Wq      = (const float*)d_in[6];
  const float* Wk      = (const float*)d_in[7];
  const float* Wv      = (const float*)d_in[8];
  const float* Wb      = (const float*)d_in[9];
  const float* Wg      = (const float*)d_in[10];
  const float* bg      = (const float*)d_in[11];
  const float* Wout    = (const float*)d_in[12];
  const float* bout    = (const float*)d_in[13];

  // Q,K (bf16) live inside d_out (2 * L*L*128 u16 == out_size * 4 bytes);
  // fully consumed by k2b before k4 overwrites d_out with the result.
  u16* Qb = (u16*)d_out;
  u16* Kb = Qb + (size_t)LL * LL * DP;

  char* ws = (char*)d_ws;
  const size_t BF_PLANE = (size_t)LL * LL * DP * 2;  // 37748736 B
  u16*   Vtb  = (u16*)ws;
  u16*   Gtb  = (u16*)(ws + BF_PLANE);
  float* part = (float*)(ws + 2 * BF_PLANE);                     // 36 planes fp32
  u16*   abf  = (u16*)(ws + 2 * BF_PLANE + 36 * SZROW * 4);
  u16*   wbf  = (u16*)(ws + 2 * BF_PLANE + 36 * SZROW * 4 + 4 * SZROW * 2);
  float* out  = (float*)d_out;

  k_prep<<<dim3(128, 5), 128, 0, stream>>>(Wq, Wk, Wv, Wg, Wout, wbf);
  k1_ln_proj<<<dim3(6, 384), 256, 0, stream>>>(pair, gamma_p, beta_p, wbf, bg, Qb, Kb, Vtb, Gtb);
  k2a_bias<<<dim3(18432), 256, 0, stream>>>(bias, gamma_b, beta_b, Wb, part);
  k2b_qk<<<dim3(8, 8, 8), 256, 0, stream>>>(Qb, Kb, part);
  k3_softmax<<<dim3(384, 4), 384, 0, stream>>>(part, abf);
  k4_out<<<dim3(6, 384), 256, 0, stream>>>(abf, Vtb, Gtb, wbf + 4 * DP * DP, bout, out);
}